// Round 16
// baseline (224.100 us; speedup 1.0000x reference)
//
#include <hip/hip_runtime.h>
#include <math.h>

#define BATCH 8
#define SEQ   1024
#define DMODEL 512
#define NHEADS 8
#define DKV   64
#define DFF   2048
#define ROWS  (BATCH * SEQ)   // 8192
#define QKLD  1024            // row stride of fused Q|K buffer
#define L2E_8 0.18033688011112042f   // log2(e)/8 folded into Q -> exp2(S') == e^(S/8)

typedef __attribute__((ext_vector_type(8))) short short8;
typedef __attribute__((ext_vector_type(4))) float f32x4;

__device__ __forceinline__ short f2bf(float f) {
    unsigned u = __float_as_uint(f);
    u += 0x7FFFu + ((u >> 16) & 1u);          // round-to-nearest-even
    return (short)(u >> 16);
}
__device__ __forceinline__ float bf2f(short s) {
    return __uint_as_float(((unsigned)(unsigned short)s) << 16);
}

// async global->LDS, 16B per lane; lds base must be wave-uniform
#define GLD16(g, l) __builtin_amdgcn_global_load_lds( \
    (const __attribute__((address_space(1))) void*)(g), \
    (__attribute__((address_space(3))) void*)(l), 16, 0, 0)

// Stage a 128x32 bf16 tile (row-major, row stride ld) into lds[128*32].
__device__ __forceinline__ void stage128x32(const short* __restrict__ g, int ld,
                                            short* lds, int tid) {
    const int w = tid >> 6;
#pragma unroll
    for (int i = 0; i < 2; ++i) {
        const int L = i * 256 + tid;
        const int r = L >> 2, c = (L & 3) << 3;
        GLD16(g + (size_t)r * ld + c, lds + (size_t)(i * 256 + (w << 6)) * 8);
    }
}

// Stage a 64x32 bf16 tile (row-major, row stride ld) into lds[64*32].
__device__ __forceinline__ void stage64x32(const short* __restrict__ g, int ld,
                                           short* lds, int tid) {
    const int w = tid >> 6;
    const int r = tid >> 2, c = (tid & 3) << 3;
    GLD16(g + (size_t)r * ld + c, lds + (size_t)(w << 6) * 8);
}

// ---------------------------------------------------------------------------
// bf16 MFMA GEMM: C[M,N] = A[M,K] @ Bt[N,K]^T. 128x128 tile, BK=32, 4 waves.
// Swapped operands -> C^T fragments -> float4/short4 epilogue stores.
// 2-phase double-buffered staging. XCD-bijective swizzle.
// QKV_MODE: A is the raw f32 X — reg-staged (issue loads early, convert+
// ds_write after the MFMA phase = T14 split). cols<qcols scaled by log2e/8;
// V-blocks (n0>=1024) transpose through LDS, coalesced short8 Vt stores.
// NOTE: no setprio here — m190 measured it hurts lockstep GEMMs.
// ---------------------------------------------------------------------------
template<int OUT_BF16, int RELU, int QKV_MODE>
__global__ __launch_bounds__(256) void gemm_bt(const void* __restrict__ Av,
                                               const short* __restrict__ Bt,
                                               void* __restrict__ Cv,
                                               int K, int lda, int ldb, int ldc,
                                               int qcols, short* __restrict__ Vt) {
    __shared__ short smem[16384];      // 32KB: As dbuf [0,8192) | Bs dbuf [8192,16384)
    short* const Asb = smem;           // As[cur] = Asb + cur*4096
    short* const Bsb = smem + 8192;    // Bs[cur] = Bsb + cur*4096
    const int tid = threadIdx.x;

    const int nx = gridDim.x;
    const int nwg = nx * gridDim.y;
    const int flat = blockIdx.y * nx + blockIdx.x;
    const int swz = (flat & 7) * (nwg >> 3) + (flat >> 3);
    const int m0 = (swz / nx) * 128, n0 = (swz % nx) * 128;

    const int w = tid >> 6, lane = tid & 63;
    const int wr = (w >> 1) * 64, wc = (w & 1) * 64;
    const int lrow = lane & 15, hi = lane >> 4;

    f32x4 acc[4][4];
#pragma unroll
    for (int m = 0; m < 4; ++m)
#pragma unroll
        for (int n = 0; n < 4; ++n) acc[m][n] = {0.f, 0.f, 0.f, 0.f};

    const short* Ab = (const short*)Av + (size_t)m0 * lda;   // QKV_MODE==0
    const float* Af = (const float*)Av;                      // QKV_MODE==1
    const short* Bb = Bt + (size_t)n0 * ldb;
    const int nt = K >> 5;

    // prologue: stage tile 0
    if (QKV_MODE) {
#pragma unroll
        for (int i = 0; i < 2; ++i) {
            const int L = i * 256 + tid;
            const int r = L >> 2, c = (L & 3) << 3;
            const float4* s = (const float4*)(Af + (size_t)(m0 + r) * lda + c);
            const float4 x = s[0], y = s[1];
            short8 o = { f2bf(x.x), f2bf(x.y), f2bf(x.z), f2bf(x.w),
                         f2bf(y.x), f2bf(y.y), f2bf(y.z), f2bf(y.w) };
            *(short8*)&Asb[(size_t)L * 8] = o;
        }
    } else {
        stage128x32(Ab, lda, Asb, tid);
    }
    stage128x32(Bb, ldb, Bsb, tid);
    __syncthreads();

    int cur = 0;
    for (int t = 0; t < nt; ++t) {
        float4 ax[2], ay[2];
        if (t + 1 < nt) {
            if (QKV_MODE) {
                // issue f32 loads early; convert+write after MFMA (latency hidden)
#pragma unroll
                for (int i = 0; i < 2; ++i) {
                    const int L = i * 256 + tid;
                    const int r = L >> 2, c = (L & 3) << 3;
                    const float4* s = (const float4*)(Af + (size_t)(m0 + r) * lda + (t + 1) * 32 + c);
                    ax[i] = s[0]; ay[i] = s[1];
                }
            } else {
                stage128x32(Ab + (size_t)(t + 1) * 32, lda, Asb + (cur ^ 1) * 4096, tid);
            }
            stage128x32(Bb + (size_t)(t + 1) * 32, ldb, Bsb + (cur ^ 1) * 4096, tid);
        }

        short8 af[4], bfr[4];
#pragma unroll
        for (int m = 0; m < 4; ++m)
            af[m] = *(const short8*)&Asb[cur * 4096 + (wr + m * 16 + lrow) * 32 + hi * 8];
#pragma unroll
        for (int n = 0; n < 4; ++n)
            bfr[n] = *(const short8*)&Bsb[cur * 4096 + (wc + n * 16 + lrow) * 32 + hi * 8];
#pragma unroll
        for (int m = 0; m < 4; ++m)
#pragma unroll
            for (int n = 0; n < 4; ++n)
                acc[m][n] = __builtin_amdgcn_mfma_f32_16x16x32_bf16(bfr[n], af[m], acc[m][n], 0, 0, 0);

        if (QKV_MODE && t + 1 < nt) {
#pragma unroll
            for (int i = 0; i < 2; ++i) {
                const int L = i * 256 + tid;
                short8 o = { f2bf(ax[i].x), f2bf(ax[i].y), f2bf(ax[i].z), f2bf(ax[i].w),
                             f2bf(ay[i].x), f2bf(ay[i].y), f2bf(ay[i].z), f2bf(ay[i].w) };
                *(short8*)&Asb[(cur ^ 1) * 4096 + (size_t)L * 8] = o;
            }
        }
        __syncthreads();
        cur ^= 1;
    }

    const int orow = m0 + wr + lrow;
    const int ocol0 = n0 + wc + hi * 4;

    if (QKV_MODE && n0 >= 1024) {
        // V block: transpose via LDS (smem free after final barrier).
        char* tb = (char*)smem;
#pragma unroll
        for (int m = 0; m < 4; ++m) {
            const int s_local = wr + m * 16 + lrow;
#pragma unroll
            for (int n = 0; n < 4; ++n) {
                const int d0 = wc + hi * 4 + n * 16;
#pragma unroll
                for (int r = 0; r < 4; ++r) {
                    const int dl = d0 + r;
                    *(short*)(tb + ((dl * 256 + s_local * 2) ^ ((dl & 7) << 4))) =
                        f2bf(acc[m][n][r]);
                }
            }
        }
        __syncthreads();
        const int b = m0 >> 10, s0 = m0 & 1023;
        const int colbase = n0 - 1024;          // h*64+d == colbase + dl
#pragma unroll
        for (int i = 0; i < 8; ++i) {
            const int c = i * 256 + tid;
            const int dl = c >> 4, sc = c & 15;
            short8 v = *(short8*)(tb + ((dl * 256 + sc * 16) ^ ((dl & 7) << 4)));
            *(short8*)(Vt + (size_t)(b * 512 + colbase + dl) * SEQ + s0 + sc * 8) = v;
        }
        return;
    }

#pragma unroll
    for (int m = 0; m < 4; ++m)
#pragma unroll
        for (int n = 0; n < 4; ++n) {
            const int col = ocol0 + n * 16;
            const float cs = (QKV_MODE && col < qcols) ? L2E_8 : 1.0f;
            float v0 = acc[m][n][0], v1 = acc[m][n][1], v2 = acc[m][n][2], v3 = acc[m][n][3];
            if (RELU) {
                v0 = fmaxf(v0, 0.f); v1 = fmaxf(v1, 0.f);
                v2 = fmaxf(v2, 0.f); v3 = fmaxf(v3, 0.f);
            }
            v0 *= cs; v1 *= cs; v2 *= cs; v3 *= cs;
            const size_t off = (size_t)(orow + m * 16) * ldc + col;
            if (OUT_BF16) {
                short4 st = { f2bf(v0), f2bf(v1), f2bf(v2), f2bf(v3) };
                *(short4*)((short*)Cv + off) = st;
            } else {
                float4 st = { v0, v1, v2, v3 };
                *(float4*)((float*)Cv + off) = st;
            }
        }
}

// ---------------------------------------------------------------------------
// Narrow-N bf16 GEMM: tile 128x64, BK=32, 4 waves (2M x 2N), wave = 64x32
// (acc[4][2]). For N=512 GEMMs (out-proj, FFN2): grid (8,64) = 512 blocks
// -> 2 blocks/CU co-resident. LDS 24KB double-buffered. Swapped operands.
// ---------------------------------------------------------------------------
__global__ __launch_bounds__(256) void gemm_n64(const short* __restrict__ A,
                                                const short* __restrict__ Bt,
                                                short* __restrict__ C,
                                                int K, int lda, int ldb, int ldc) {
    __shared__ short As[2][128 * 32];
    __shared__ short Bs[2][64 * 32];
    const int tid = threadIdx.x;

    const int nx = gridDim.x;                     // n-tiles (64-wide)
    const int nwg = nx * gridDim.y;
    const int flat = blockIdx.y * nx + blockIdx.x;
    const int swz = (flat & 7) * (nwg >> 3) + (flat >> 3);
    const int m0 = (swz / nx) * 128, n0 = (swz % nx) * 64;

    const int w = tid >> 6, lane = tid & 63;
    const int wr = (w >> 1) * 64, wc = (w & 1) * 32;
    const int lrow = lane & 15, hi = lane >> 4;

    f32x4 acc[4][2];
#pragma unroll
    for (int m = 0; m < 4; ++m)
#pragma unroll
        for (int n = 0; n < 2; ++n) acc[m][n] = {0.f, 0.f, 0.f, 0.f};

    const short* Ab = A + (size_t)m0 * lda;
    const short* Bb = Bt + (size_t)n0 * ldb;
    const int nt = K >> 5;

    stage128x32(Ab, lda, As[0], tid);
    stage64x32(Bb, ldb, Bs[0], tid);
    __syncthreads();

    int cur = 0;
    for (int t = 0; t < nt; ++t) {
        if (t + 1 < nt) {
            stage128x32(Ab + (size_t)(t + 1) * 32, lda, As[cur ^ 1], tid);
            stage64x32(Bb + (size_t)(t + 1) * 32, ldb, Bs[cur ^ 1], tid);
        }
        short8 af[4], bfr[2];
#pragma unroll
        for (int m = 0; m < 4; ++m)
            af[m] = *(const short8*)&As[cur][(size_t)(wr + m * 16 + lrow) * 32 + hi * 8];
#pragma unroll
        for (int n = 0; n < 2; ++n)
            bfr[n] = *(const short8*)&Bs[cur][(size_t)(wc + n * 16 + lrow) * 32 + hi * 8];
#pragma unroll
        for (int m = 0; m < 4; ++m)
#pragma unroll
            for (int n = 0; n < 2; ++n)
                acc[m][n] = __builtin_amdgcn_mfma_f32_16x16x32_bf16(bfr[n], af[m], acc[m][n], 0, 0, 0);
        __syncthreads();
        cur ^= 1;
    }

    const int orow = m0 + wr + lrow;
    const int ocol0 = n0 + wc + hi * 4;
#pragma unroll
    for (int m = 0; m < 4; ++m)
#pragma unroll
        for (int n = 0; n < 2; ++n) {
            short4 st = { f2bf(acc[m][n][0]), f2bf(acc[m][n][1]),
                          f2bf(acc[m][n][2]), f2bf(acc[m][n][3]) };
            *(short4*)(C + (size_t)(orow + m * 16) * ldc + ocol0 + n * 16) = st;
        }
}

// ---------------------------------------------------------------------------
// Fused causal attention for one (q-tile of 128, bh). Round-12 body,
// validated 5x; block->(bh,it) mapping FROZEN (two remap attempts failed).
// THIS ROUND: T5 s_setprio(1) wrapped around the MFMA clusters only (QK^T
// and PV). Scheduler hint, semantically neutral; pays here because the 2
// co-resident blocks/CU sit at different (it, pass) phases (m191: +4-7%).
// ---------------------------------------------------------------------------
__global__ __launch_bounds__(256, 2) void fused_attn(const short* __restrict__ Q,
                                                     const short* __restrict__ K,
                                                     const short* __restrict__ Vt,
                                                     float* __restrict__ attnP,
                                                     short* __restrict__ ctx) {
    const int flat = blockIdx.y * 8 + blockIdx.x;
    const int swz  = (flat & 7) * 64 + (flat >> 3);   // bijective, nwg = 512
    const int bh = swz >> 3, it = 7 - (swz & 7);
    const int b = bh >> 3, h = bh & 7;

    __shared__ short Qs[128 * 64];        // 16KB [q][dk] swizzled
    __shared__ short KVs[2][128 * 64];    // 32KB pass1: [0]=K,[1]=V; pass2: K dbuf
    __shared__ short Ps[128 * 128];       // 32KB [q][k] swizzled (pass 1 PV)
    float* rsum = (float*)Ps;             // overlay after last PV

    const int tid = threadIdx.x;
    const int w = tid >> 6, lane = tid & 63;
    const int wr = (w >> 1) * 64, wc2 = (w & 1);
    const int lrow = lane & 15, hi = lane >> 4;
    const size_t base = (size_t)b * SEQ * QKLD + h * DKV;
    float* aprow = attnP + (size_t)bh * SEQ * SEQ;

    auto stage_k = [&](int kt, short* dst) {
#pragma unroll
        for (int i = 0; i < 4; ++i) {
            const int L = i * 256 + tid;
            const int r = L >> 3, sc = ((L & 7) ^ (r & 7)) * 8;
            GLD16(K + base + (size_t)(kt * 128 + r) * QKLD + sc,
                  dst + (size_t)(i * 256 + (w << 6)) * 8);
        }
    };
    auto stage_v = [&](int kt, short* dst) {
#pragma unroll
        for (int i = 0; i < 4; ++i) {
            const int L = i * 256 + tid;
            const int r = L >> 4, sc = ((L & 15) ^ (r & 7)) * 8;
            GLD16(Vt + (size_t)(bh * DKV + r) * SEQ + kt * 128 + sc,
                  dst + (size_t)(i * 256 + (w << 6)) * 8);
        }
    };
    auto qkt = [&](const short* Ks, f32x4 s[4][4]) {
#pragma unroll
        for (int m = 0; m < 4; ++m)
#pragma unroll
            for (int n = 0; n < 4; ++n) s[m][n] = {0.f, 0.f, 0.f, 0.f};
#pragma unroll
        for (int sk = 0; sk < 2; ++sk) {
            short8 qf[4], kf[4];
#pragma unroll
            for (int m = 0; m < 4; ++m) {
                const int r = wr + m * 16 + lrow;
                qf[m] = *(const short8*)((const char*)Qs + r * 128 + ((hi * 16 + sk * 64) ^ ((r & 7) << 4)));
            }
#pragma unroll
            for (int n = 0; n < 4; ++n) {
                const int r = wc2 * 64 + n * 16 + lrow;
                kf[n] = *(const short8*)((const char*)Ks + r * 128 + ((hi * 16 + sk * 64) ^ ((r & 7) << 4)));
            }
            __builtin_amdgcn_s_setprio(1);
#pragma unroll
            for (int m = 0; m < 4; ++m)
#pragma unroll
                for (int n = 0; n < 4; ++n)
                    s[m][n] = __builtin_amdgcn_mfma_f32_16x16x32_bf16(kf[n], qf[m], s[m][n], 0, 0, 0);
            __builtin_amdgcn_s_setprio(0);
        }
    };

    // ---- zero the strictly-upper tile region of our 128 rows (NT) ----
    {
        const int nz4 = (7 - it) * 32;               // f32x4s per row
        if (nz4 > 0) {
            const f32x4 z = {0.f, 0.f, 0.f, 0.f};
            for (int r = tid >> 5; r < 128; r += 8) {
                f32x4* rp = (f32x4*)(aprow + (size_t)(it * 128 + r) * SEQ + (it + 1) * 128);
                for (int c = tid & 31; c < nz4; c += 32)
                    __builtin_nontemporal_store(z, rp + c);
            }
        }
    }

    // ---- stage Q (once) + K[0] + V[0] ----
#pragma unroll
    for (int i = 0; i < 4; ++i) {
        const int L = i * 256 + tid;
        const int r = L >> 3, sc = ((L & 7) ^ (r & 7)) * 8;
        GLD16(Q + base + (size_t)(it * 128 + r) * QKLD + sc,
              Qs + (size_t)(i * 256 + (w << 6)) * 8);
    }
    stage_k(0, KVs[0]);
    stage_v(0, KVs[1]);
    __syncthreads();

    // ================= pass 1: rowsums + PV (unnormalized) =================
    float rs[4] = {0.f, 0.f, 0.f, 0.f};
    f32x4 o[4][2];
#pragma unroll
    for (int m = 0; m < 4; ++m)
#pragma unroll
        for (int n = 0; n < 2; ++n) o[m][n] = {0.f, 0.f, 0.f, 0.f};

    for (int kt = 0; kt <= it; ++kt) {
        f32x4 s[4][4];
        qkt(KVs[0], s);

        const bool diag = (kt == it);
#pragma unroll
        for (int m = 0; m < 4; ++m) {
            const int q = wr + m * 16 + lrow;
#pragma unroll
            for (int n = 0; n < 4; ++n) {
                const int k0 = wc2 * 64 + n * 16 + hi * 4;
                float p0 = exp2f(s[m][n][0]);
                float p1 = exp2f(s[m][n][1]);
                float p2 = exp2f(s[m][n][2]);
                float p3 = exp2f(s[m][n][3]);
                if (diag) {
                    if (k0 + 0 > q) p0 = 0.f;
                    if (k0 + 1 > q) p1 = 0.f;
                    if (k0 + 2 > q) p2 = 0.f;
                    if (k0 + 3 > q) p3 = 0.f;
                }
                rs[m] += (p0 + p1) + (p2 + p3);
                short4 ph = { f2bf(p0), f2bf(p1), f2bf(p2), f2bf(p3) };
                *(short4*)((char*)Ps + q * 256 + ((k0 * 2) ^ ((q & 7) << 4))) = ph;
            }
        }
        __syncthreads();                          // A: Ps visible, K buffer free
        if (kt < it) stage_k(kt + 1, KVs[0]);     // K[kt+1] flies under PV

        // PV: o += mfma(V, P) over full 128-k tile
#pragma unroll
        for (int sk = 0; sk < 4; ++sk) {
            short8 pf[4], vf[2];
#pragma unroll
            for (int m = 0; m < 4; ++m) {
                const int r = wr + m * 16 + lrow;
                pf[m] = *(const short8*)((const char*)Ps + r * 256 + ((hi * 16 + sk * 64) ^ ((r & 7) << 4)));
            }
#pragma unroll
            for (int n = 0; n < 2; ++n) {
                const int r = wc2 * 32 + n * 16 + lrow;
                vf[n] = *(const short8*)((const char*)KVs[1] + r * 256 + ((hi * 16 + sk * 64) ^ ((r & 7) << 4)));
            }
            __builtin_amdgcn_s_setprio(1);
#pragma unroll
            for (int m = 0; m < 4; ++m)
#pragma unroll
                for (int n = 0; n < 2; ++n)
                    o[m][n] = __builtin_amdgcn_mfma_f32_16x16x32_bf16(vf[n], pf[m], o[m][n], 0, 0, 0);
            __builtin_amdgcn_s_setprio(0);
        }
        __syncthreads();                          // B: drains K[kt+1]; V buffer free
        if (kt < it) stage_v(kt + 1, KVs[1]);     // V[kt+1] flies under next QK^T
    }

    // ---- rowsum reduce: lanes sharing lane&15 hold the same q-row ----
#pragma unroll
    for (int m = 0; m < 4; ++m) {
        rs[m] += __shfl_xor(rs[m], 16);
        rs[m] += __shfl_xor(rs[m], 32);
    }
    if (lane < 16) {
#pragma unroll
        for (int m = 0; m < 4; ++m)
            rsum[wc2 * 128 + wr + m * 16 + lane] = rs[m];
    }
    __syncthreads();
    if (tid < 128) rsum[tid] = 1.0f / (rsum[tid] + rsum[128 + tid]);
    __syncthreads();
    float inv[4];
#pragma unroll
    for (int m = 0; m < 4; ++m) inv[m] = rsum[wr + m * 16 + lrow];

    // ---- ctx = o * inv (bf16, short4) ----
#pragma unroll
    for (int m = 0; m < 4; ++m) {
        const int q = it * 128 + wr + m * 16 + lrow;
#pragma unroll
        for (int n = 0; n < 2; ++n) {
            const int d = h * DKV + wc2 * 32 + n * 16 + hi * 4;
            short4 st = { f2bf(o[m][n][0] * inv[m]), f2bf(o[m][n][1] * inv[m]),
                          f2bf(o[m][n][2] * inv[m]), f2bf(o[m][n][3] * inv[m]) };
            *(short4*)(ctx + (size_t)(b * SEQ + q) * DMODEL + d) = st;
        }
    }

    // ================= pass 2: write normalized P (K dbuf, 1 barrier/iter) ==
    stage_k(0, KVs[0]);
    __syncthreads();
    int cur = 0;
    for (int kt = 0; kt <= it; ++kt) {
        if (kt < it) stage_k(kt + 1, KVs[cur ^ 1]);

        f32x4 s[4][4];
        qkt(KVs[cur], s);

        const bool diag = (kt == it);
#pragma unroll
        for (int m = 0; m < 4; ++m) {
            const int q = wr + m * 16 + lrow;
#pragma unroll
            for (int n = 0; n < 4; ++n) {
                const int k0 = wc2 * 64 + n * 16 + hi * 4;
                float p0 = exp2f(s[m][n][0]);
                float p1 = exp2f(s[m][n][1]);
                float p2 = exp2f(s[m][n][2]);
                float p3 = exp2f(s[m][n][3]);
                if (diag) {
                    if (k0 + 0 > q) p0 = 0.f;
                    if (k0 + 1 > q) p1 = 0.f;
                    if (k0 + 2 > q) p2 = 0.f;
                    if (k0 + 3 > q) p3 = 0.f;
                }
                f32x4 pv4 = { p0 * inv[m], p1 * inv[m], p2 * inv[m], p3 * inv[m] };
                __builtin_nontemporal_store(pv4,
                    (f32x4*)(aprow + (size_t)(it * 128 + q) * SEQ + kt * 128 + k0));
            }
        }
        __syncthreads();            // drains next K tile; frees cur buffer
        cur ^= 1;
    }
}

// ---------------------------------------------------------------------------
// out = LayerNorm(xin + res)*g + b. xin f32 or bf16; res f32 or bf16;
// emits f32 and/or bf16.
// ---------------------------------------------------------------------------
template<int XIN_BF16, int RES_BF16, int OUT_F32, int OUT_BF16>
__global__ __launch_bounds__(128) void residual_ln(const void* __restrict__ xin,
                                                   const void* __restrict__ res,
                                                   const float* __restrict__ g,
                                                   const float* __restrict__ beta,
                                                   float* __restrict__ outf,
                                                   short* __restrict__ outh) {
    const int row = blockIdx.x;
    const int tid = threadIdx.x;

    float4 v;
    if (XIN_BF16) {
        const short4 xx = ((const short4*)((const short*)xin + (size_t)row * DMODEL))[tid];
        v.x = bf2f(xx.x); v.y = bf2f(xx.y); v.z = bf2f(xx.z); v.w = bf2f(xx.w);
    } else {
        v = ((const float4*)((const float*)xin + (size_t)row * DMODEL))[tid];
    }
    if (RES_BF16) {
        const short4 rr = ((const short4*)((const short*)res + (size_t)row * DMODEL))[tid];
        v.x += bf2f(rr.x); v.y += bf2f(rr.y); v.z += bf2f(rr.z); v.w += bf2f(rr.w);
    } else {
        const float4 rr = ((const float4*)((const float*)res + (size_t)row * DMODEL))[tid];
        v.x += rr.x; v.y += rr.y; v.z += rr.z; v.w += rr.w;
    }

    float sum = v.x + v.y + v.z + v.w;
    float sq  = v.x * v.x + v.y * v.y + v.z * v.z + v.w * v.w;
#pragma unroll
    for (int off = 32; off > 0; off >>= 1) {
        sum += __shfl_down(sum, off);
        sq  += __shfl_down(sq, off);
    }
    __shared__ float s_sum[2], s_sq[2];
    const int wid = tid >> 6, lane = tid & 63;
    if (lane == 0) { s_sum[wid] = sum; s_sq[wid] = sq; }
    __syncthreads();

    const float tsum = s_sum[0] + s_sum[1];
    const float tsq  = s_sq[0] + s_sq[1];
    const float mu   = tsum * (1.0f / DMODEL);
    const float var  = tsq * (1.0f / DMODEL) - mu * mu;
    const float rstd = rsqrtf(var + 1e-5f);

    const float4 gg = ((const float4*)g)[tid];
    const float4 bb = ((const float4*)beta)[tid];
    float4 o;
    o.x = (v.x - mu) * rstd * gg.x + bb.x;
    o.y = (v.y - mu) * rstd * gg.y + bb.y;
    o.z = (v.z - mu) * rstd * gg.z + bb.z;
    o.w = (v.w - mu) * rstd * gg.w + bb.w;
    if (OUT_F32) ((float4*)(outf + (size_t)row * DMODEL))[tid] = o;
    if (OUT_BF16) {
        short4 oh = { f2bf(o.x), f2bf(o.y), f2bf(o.z), f2bf(o.w) };
        ((short4*)(outh + (size_t)row * DMODEL))[tid] = oh;
    }
}

// ---------------------------------------------------------------------------
// Consolidated prep: all 6 weight transposes (32x32 tiles, f32 -> bf16
// transposed). X conversion not needed (QKV GEMM reads X directly).
// ---------------------------------------------------------------------------
__global__ __launch_bounds__(256) void prep_all(const float* __restrict__ w_q,
                                                const float* __restrict__ w_k,
                                                const float* __restrict__ w_v,
                                                const float* __restrict__ w_o,
                                                const float* __restrict__ w1,
                                                const float* __restrict__ w2,
                                                short* __restrict__ wqkvt,
                                                short* __restrict__ wot,
                                                short* __restrict__ w1t,
                                                short* __restrict__ w2t) {
    const int t = blockIdx.x;
    const int tid = threadIdx.x;
    const float* W; short* Wt; int K, N, tile;
    if (t < 1024) {                       // wq, wk, wv, wo (256 tiles each)
        const int wsel = t >> 8; tile = t & 255;
        K = 512; N = 512;
        W  = (wsel == 0) ? w_q : (wsel == 1) ? w_k : (wsel == 2) ? w_v : w_o;
        Wt = (wsel < 3) ? (wqkvt + (size_t)wsel * 512 * 512) : wot;
    } else if (t < 2048) { tile = t - 1024; K = 512;  N = 2048; W = w1; Wt = w1t; }
    else                 { tile = t - 2048; K = 2048; N = 512;  W = w2; Wt = w2t; }

    const int ntx = N >> 5;
    const int n0 = (tile % ntx) * 32, k0 = (tile / ntx) * 32;
    const int tx = tid & 31, ty = tid >> 5;

    __shared__ float tb[32][33];
#pragma unroll
    for (int i = 0; i < 4; ++i)
        tb[ty + i * 8][tx] = W[(size_t)(k0 + ty + i * 8) * N + n0 + tx];
    __syncthreads();
#pragma unroll
    for (int i = 0; i < 4; ++i)
        Wt[(size_t)(n0 + ty + i * 8) * K + k0 + tx] = f2bf(tb[tx][ty + i * 8]);
}

// ---------------------------------------------------------------------------
extern "C" void kernel_launch(void* const* d_in, const int* in_sizes, int n_in,
                              void* d_out, int out_size, void* d_ws, size_t ws_size,
                              hipStream_t stream) {
    const float* X    = (const float*)d_in[0];
    // d_in[1] = mask: causal triu -> handled analytically
    const float* w_q  = (const float*)d_in[2];
    const float* w_k  = (const float*)d_in[3];
    const float* w_v  = (const float*)d_in[4];
    const float* w_o  = (const float*)d_in[5];
    const float* ln1g = (const float*)d_in[6];
    const float* ln1b = (const float*)d_in[7];
    const float* w1   = (const float*)d_in[8];
    const float* w2   = (const float*)d_in[9];
    const float* ln2g = (const float*)d_in[10];
    const float* ln2b = (const float*)d_in[11];

    float* out   = (float*)d_out;                       // [8192, 512] f32
    float* attnP = out + (size_t)ROWS * DMODEL;         // [64, 1024, 1024] f32

    // workspace (shorts). M = 2^20 shorts = 2MB. Total 64MB.
    const size_t M = 1u << 20;
    short* ws    = (short*)d_ws;
    short* qkv   = ws;               // [ 0, 8M) Q|K [8192][1024]
    short* Vt    = ws + 8 * M;       // [ 8,12M) [64*64][1024] V^T
    short* ctxh  = ws + 12 * M;      // [12,16M)
    short* aoutH = ws + 16 * M;      // [16,20M)
    short* wqkvt = ws + 24 * M;      // [1536][512] = 0.75M shorts
    short* wot   = wqkvt + 786432;   // [512][512]  = 0.25M
    short* w1t   = ws + 25 * M;      // [2048][512] = 1M
    short* w2t   = ws + 26 * M;      // [512][2048] = 1M
    short* oph   = ws + 28 * M;      // [28,32M) out-proj bf16 (pre-LN1)
    short* ffnh  = ws + 28 * M;      // [28,32M) FFN2 bf16 (pre-LN2; oph dead)
    short* hbuf  = ws;               // [0,16M) FFN hidden [8192][2048]

    // prep: weight transposes (one dispatch)
    prep_all<<<dim3(3072), dim3(256), 0, stream>>>(w_q, w_k, w_v, w_o, w1, w2,
                                                   wqkvt, wot, w1t, w2t);

    // 1) fused QKV projection: A = X f32 (reg-staged + converted in-kernel);
    //    Q (scaled by log2e/8) | K -> qkv; V -> Vt transposed
    gemm_bt<1, 0, 1><<<dim3(12, 64), dim3(256), 0, stream>>>(X, wqkvt, qkv,
                                                             DMODEL, DMODEL, DMODEL, QKLD, 512, Vt);

    // 2) fused attention: ctx + attnP (probs incl. zeros, NT stores)
    fused_attn<<<dim3(8, 64), dim3(256), 0, stream>>>(qkv, qkv + 512, Vt, attnP, ctxh);

    // 3) out-proj (narrow-N: 512 blocks, bf16 -> oph) + LN1 (-> bf16 aoutH)
    gemm_n64<<<dim3(8, 64), dim3(256), 0, stream>>>(ctxh, wot, oph,
                                                    DMODEL, DMODEL, DMODEL, DMODEL);
    residual_ln<1, 0, 0, 1><<<dim3(ROWS), dim3(128), 0, stream>>>(oph, X, ln1g, ln1b, nullptr, aoutH);

    // 4) FFN: relu GEMM -> hbuf (bf16); FFN2 narrow-N -> ffnh (bf16); LN2 -> f32 out
    gemm_bt<1, 1, 0><<<dim3(16, 64), dim3(256), 0, stream>>>(aoutH, w1t, hbuf,
                                                             DMODEL, DMODEL, DMODEL, DFF, 0, nullptr);
    gemm_n64<<<dim3(8, 64), dim3(256), 0, stream>>>(hbuf, w2t, ffnh,
                                                    DFF, DFF, DFF, DMODEL);
    residual_ln<1, 1, 1, 0><<<dim3(ROWS), dim3(128), 0, stream>>>(ffnh, aoutH, ln2g, ln2b, out, nullptr);
}

// Round 17
// 218.716 us; speedup vs baseline: 1.0246x; 1.0246x over previous
//
#include <hip/hip_runtime.h>
#include <math.h>

#define BATCH 8
#define SEQ   1024
#define DMODEL 512
#define NHEADS 8
#define DKV   64
#define DFF   2048
#define ROWS  (BATCH * SEQ)   // 8192
#define QKLD  1024            // row stride of fused Q|K buffer
#define L2E_8 0.18033688011112042f   // log2(e)/8 folded into Q -> exp2(S') == e^(S/8)

typedef __attribute__((ext_vector_type(8))) short short8;
typedef __attribute__((ext_vector_type(4))) float f32x4;

__device__ __forceinline__ short f2bf(float f) {
    unsigned u = __float_as_uint(f);
    u += 0x7FFFu + ((u >> 16) & 1u);          // round-to-nearest-even
    return (short)(u >> 16);
}
__device__ __forceinline__ float bf2f(short s) {
    return __uint_as_float(((unsigned)(unsigned short)s) << 16);
}

// async global->LDS, 16B per lane; lds base must be wave-uniform
#define GLD16(g, l) __builtin_amdgcn_global_load_lds( \
    (const __attribute__((address_space(1))) void*)(g), \
    (__attribute__((address_space(3))) void*)(l), 16, 0, 0)

// Stage a 128x32 bf16 tile (row-major, row stride ld) into lds[128*32].
__device__ __forceinline__ void stage128x32(const short* __restrict__ g, int ld,
                                            short* lds, int tid) {
    const int w = tid >> 6;
#pragma unroll
    for (int i = 0; i < 2; ++i) {
        const int L = i * 256 + tid;
        const int r = L >> 2, c = (L & 3) << 3;
        GLD16(g + (size_t)r * ld + c, lds + (size_t)(i * 256 + (w << 6)) * 8);
    }
}

// Stage a 64x32 bf16 tile (row-major, row stride ld) into lds[64*32].
__device__ __forceinline__ void stage64x32(const short* __restrict__ g, int ld,
                                           short* lds, int tid) {
    const int w = tid >> 6;
    const int r = tid >> 2, c = (tid & 3) << 3;
    GLD16(g + (size_t)r * ld + c, lds + (size_t)(w << 6) * 8);
}

// ---------------------------------------------------------------------------
// bf16 MFMA GEMM: C[M,N] = A[M,K] @ Bt[N,K]^T. 128x128 tile, BK=32, 4 waves.
// Swapped operands -> C^T fragments -> float4/short4 epilogue stores.
// 2-phase double-buffered staging. XCD-bijective swizzle.
// QKV_MODE: A is the raw f32 X — reg-staged (issue loads early, convert+
// ds_write after the MFMA phase = T14 split). cols<qcols scaled by log2e/8;
// V-blocks (n0>=1024) transpose through LDS, coalesced short8 Vt stores.
// ---------------------------------------------------------------------------
template<int OUT_BF16, int RELU, int QKV_MODE>
__global__ __launch_bounds__(256) void gemm_bt(const void* __restrict__ Av,
                                               const short* __restrict__ Bt,
                                               void* __restrict__ Cv,
                                               int K, int lda, int ldb, int ldc,
                                               int qcols, short* __restrict__ Vt) {
    __shared__ short smem[16384];      // 32KB: As dbuf [0,8192) | Bs dbuf [8192,16384)
    short* const Asb = smem;           // As[cur] = Asb + cur*4096
    short* const Bsb = smem + 8192;    // Bs[cur] = Bsb + cur*4096
    const int tid = threadIdx.x;

    const int nx = gridDim.x;
    const int nwg = nx * gridDim.y;
    const int flat = blockIdx.y * nx + blockIdx.x;
    const int swz = (flat & 7) * (nwg >> 3) + (flat >> 3);
    const int m0 = (swz / nx) * 128, n0 = (swz % nx) * 128;

    const int w = tid >> 6, lane = tid & 63;
    const int wr = (w >> 1) * 64, wc = (w & 1) * 64;
    const int lrow = lane & 15, hi = lane >> 4;

    f32x4 acc[4][4];
#pragma unroll
    for (int m = 0; m < 4; ++m)
#pragma unroll
        for (int n = 0; n < 4; ++n) acc[m][n] = {0.f, 0.f, 0.f, 0.f};

    const short* Ab = (const short*)Av + (size_t)m0 * lda;   // QKV_MODE==0
    const float* Af = (const float*)Av;                      // QKV_MODE==1
    const short* Bb = Bt + (size_t)n0 * ldb;
    const int nt = K >> 5;

    // prologue: stage tile 0
    if (QKV_MODE) {
#pragma unroll
        for (int i = 0; i < 2; ++i) {
            const int L = i * 256 + tid;
            const int r = L >> 2, c = (L & 3) << 3;
            const float4* s = (const float4*)(Af + (size_t)(m0 + r) * lda + c);
            const float4 x = s[0], y = s[1];
            short8 o = { f2bf(x.x), f2bf(x.y), f2bf(x.z), f2bf(x.w),
                         f2bf(y.x), f2bf(y.y), f2bf(y.z), f2bf(y.w) };
            *(short8*)&Asb[(size_t)L * 8] = o;
        }
    } else {
        stage128x32(Ab, lda, Asb, tid);
    }
    stage128x32(Bb, ldb, Bsb, tid);
    __syncthreads();

    int cur = 0;
    for (int t = 0; t < nt; ++t) {
        float4 ax[2], ay[2];
        if (t + 1 < nt) {
            if (QKV_MODE) {
                // issue f32 loads early; convert+write after MFMA (latency hidden)
#pragma unroll
                for (int i = 0; i < 2; ++i) {
                    const int L = i * 256 + tid;
                    const int r = L >> 2, c = (L & 3) << 3;
                    const float4* s = (const float4*)(Af + (size_t)(m0 + r) * lda + (t + 1) * 32 + c);
                    ax[i] = s[0]; ay[i] = s[1];
                }
            } else {
                stage128x32(Ab + (size_t)(t + 1) * 32, lda, Asb + (cur ^ 1) * 4096, tid);
            }
            stage128x32(Bb + (size_t)(t + 1) * 32, ldb, Bsb + (cur ^ 1) * 4096, tid);
        }

        short8 af[4], bfr[4];
#pragma unroll
        for (int m = 0; m < 4; ++m)
            af[m] = *(const short8*)&Asb[cur * 4096 + (wr + m * 16 + lrow) * 32 + hi * 8];
#pragma unroll
        for (int n = 0; n < 4; ++n)
            bfr[n] = *(const short8*)&Bsb[cur * 4096 + (wc + n * 16 + lrow) * 32 + hi * 8];
#pragma unroll
        for (int m = 0; m < 4; ++m)
#pragma unroll
            for (int n = 0; n < 4; ++n)
                acc[m][n] = __builtin_amdgcn_mfma_f32_16x16x32_bf16(bfr[n], af[m], acc[m][n], 0, 0, 0);

        if (QKV_MODE && t + 1 < nt) {
#pragma unroll
            for (int i = 0; i < 2; ++i) {
                const int L = i * 256 + tid;
                short8 o = { f2bf(ax[i].x), f2bf(ax[i].y), f2bf(ax[i].z), f2bf(ax[i].w),
                             f2bf(ay[i].x), f2bf(ay[i].y), f2bf(ay[i].z), f2bf(ay[i].w) };
                *(short8*)&Asb[(cur ^ 1) * 4096 + (size_t)L * 8] = o;
            }
        }
        __syncthreads();
        cur ^= 1;
    }

    const int orow = m0 + wr + lrow;
    const int ocol0 = n0 + wc + hi * 4;

    if (QKV_MODE && n0 >= 1024) {
        // V block: transpose via LDS (smem free after final barrier).
        char* tb = (char*)smem;
#pragma unroll
        for (int m = 0; m < 4; ++m) {
            const int s_local = wr + m * 16 + lrow;
#pragma unroll
            for (int n = 0; n < 4; ++n) {
                const int d0 = wc + hi * 4 + n * 16;
#pragma unroll
                for (int r = 0; r < 4; ++r) {
                    const int dl = d0 + r;
                    *(short*)(tb + ((dl * 256 + s_local * 2) ^ ((dl & 7) << 4))) =
                        f2bf(acc[m][n][r]);
                }
            }
        }
        __syncthreads();
        const int b = m0 >> 10, s0 = m0 & 1023;
        const int colbase = n0 - 1024;          // h*64+d == colbase + dl
#pragma unroll
        for (int i = 0; i < 8; ++i) {
            const int c = i * 256 + tid;
            const int dl = c >> 4, sc = c & 15;
            short8 v = *(short8*)(tb + ((dl * 256 + sc * 16) ^ ((dl & 7) << 4)));
            *(short8*)(Vt + (size_t)(b * 512 + colbase + dl) * SEQ + s0 + sc * 8) = v;
        }
        return;
    }

#pragma unroll
    for (int m = 0; m < 4; ++m)
#pragma unroll
        for (int n = 0; n < 4; ++n) {
            const int col = ocol0 + n * 16;
            const float cs = (QKV_MODE && col < qcols) ? L2E_8 : 1.0f;
            float v0 = acc[m][n][0], v1 = acc[m][n][1], v2 = acc[m][n][2], v3 = acc[m][n][3];
            if (RELU) {
                v0 = fmaxf(v0, 0.f); v1 = fmaxf(v1, 0.f);
                v2 = fmaxf(v2, 0.f); v3 = fmaxf(v3, 0.f);
            }
            v0 *= cs; v1 *= cs; v2 *= cs; v3 *= cs;
            const size_t off = (size_t)(orow + m * 16) * ldc + col;
            if (OUT_BF16) {
                short4 st = { f2bf(v0), f2bf(v1), f2bf(v2), f2bf(v3) };
                *(short4*)((short*)Cv + off) = st;
            } else {
                float4 st = { v0, v1, v2, v3 };
                *(float4*)((float*)Cv + off) = st;
            }
        }
}

// ---------------------------------------------------------------------------
// Narrow-N bf16 GEMM: tile 128x64, BK=32, 4 waves (2M x 2N), wave = 64x32
// (acc[4][2]). For N=512 GEMMs (out-proj, FFN2): grid (8,64) = 512 blocks
// -> 2 blocks/CU co-resident. LDS 24KB double-buffered. Swapped operands.
// ---------------------------------------------------------------------------
__global__ __launch_bounds__(256) void gemm_n64(const short* __restrict__ A,
                                                const short* __restrict__ Bt,
                                                short* __restrict__ C,
                                                int K, int lda, int ldb, int ldc) {
    __shared__ short As[2][128 * 32];
    __shared__ short Bs[2][64 * 32];
    const int tid = threadIdx.x;

    const int nx = gridDim.x;                     // n-tiles (64-wide)
    const int nwg = nx * gridDim.y;
    const int flat = blockIdx.y * nx + blockIdx.x;
    const int swz = (flat & 7) * (nwg >> 3) + (flat >> 3);
    const int m0 = (swz / nx) * 128, n0 = (swz % nx) * 64;

    const int w = tid >> 6, lane = tid & 63;
    const int wr = (w >> 1) * 64, wc = (w & 1) * 32;
    const int lrow = lane & 15, hi = lane >> 4;

    f32x4 acc[4][2];
#pragma unroll
    for (int m = 0; m < 4; ++m)
#pragma unroll
        for (int n = 0; n < 2; ++n) acc[m][n] = {0.f, 0.f, 0.f, 0.f};

    const short* Ab = A + (size_t)m0 * lda;
    const short* Bb = Bt + (size_t)n0 * ldb;
    const int nt = K >> 5;

    stage128x32(Ab, lda, As[0], tid);
    stage64x32(Bb, ldb, Bs[0], tid);
    __syncthreads();

    int cur = 0;
    for (int t = 0; t < nt; ++t) {
        if (t + 1 < nt) {
            stage128x32(Ab + (size_t)(t + 1) * 32, lda, As[cur ^ 1], tid);
            stage64x32(Bb + (size_t)(t + 1) * 32, ldb, Bs[cur ^ 1], tid);
        }
        short8 af[4], bfr[2];
#pragma unroll
        for (int m = 0; m < 4; ++m)
            af[m] = *(const short8*)&As[cur][(size_t)(wr + m * 16 + lrow) * 32 + hi * 8];
#pragma unroll
        for (int n = 0; n < 2; ++n)
            bfr[n] = *(const short8*)&Bs[cur][(size_t)(wc + n * 16 + lrow) * 32 + hi * 8];
#pragma unroll
        for (int m = 0; m < 4; ++m)
#pragma unroll
            for (int n = 0; n < 2; ++n)
                acc[m][n] = __builtin_amdgcn_mfma_f32_16x16x32_bf16(bfr[n], af[m], acc[m][n], 0, 0, 0);
        __syncthreads();
        cur ^= 1;
    }

    const int orow = m0 + wr + lrow;
    const int ocol0 = n0 + wc + hi * 4;
#pragma unroll
    for (int m = 0; m < 4; ++m)
#pragma unroll
        for (int n = 0; n < 2; ++n) {
            short4 st = { f2bf(acc[m][n][0]), f2bf(acc[m][n][1]),
                          f2bf(acc[m][n][2]), f2bf(acc[m][n][3]) };
            *(short4*)(C + (size_t)(orow + m * 16) * ldc + ocol0 + n * 16) = st;
        }
}

// ---------------------------------------------------------------------------
// Fused causal attention for one (q-tile of 128, bh). EXACT round-12 body
// (validated; setprio experiment reverted after measured -5us regression;
// block->(bh,it) mapping FROZEN after two failed remap attempts).
// ---------------------------------------------------------------------------
__global__ __launch_bounds__(256, 2) void fused_attn(const short* __restrict__ Q,
                                                     const short* __restrict__ K,
                                                     const short* __restrict__ Vt,
                                                     float* __restrict__ attnP,
                                                     short* __restrict__ ctx) {
    const int flat = blockIdx.y * 8 + blockIdx.x;
    const int swz  = (flat & 7) * 64 + (flat >> 3);   // bijective, nwg = 512
    const int bh = swz >> 3, it = 7 - (swz & 7);
    const int b = bh >> 3, h = bh & 7;

    __shared__ short Qs[128 * 64];        // 16KB [q][dk] swizzled
    __shared__ short KVs[2][128 * 64];    // 32KB pass1: [0]=K,[1]=V; pass2: K dbuf
    __shared__ short Ps[128 * 128];       // 32KB [q][k] swizzled (pass 1 PV)
    float* rsum = (float*)Ps;             // overlay after last PV

    const int tid = threadIdx.x;
    const int w = tid >> 6, lane = tid & 63;
    const int wr = (w >> 1) * 64, wc2 = (w & 1);
    const int lrow = lane & 15, hi = lane >> 4;
    const size_t base = (size_t)b * SEQ * QKLD + h * DKV;
    float* aprow = attnP + (size_t)bh * SEQ * SEQ;

    auto stage_k = [&](int kt, short* dst) {
#pragma unroll
        for (int i = 0; i < 4; ++i) {
            const int L = i * 256 + tid;
            const int r = L >> 3, sc = ((L & 7) ^ (r & 7)) * 8;
            GLD16(K + base + (size_t)(kt * 128 + r) * QKLD + sc,
                  dst + (size_t)(i * 256 + (w << 6)) * 8);
        }
    };
    auto stage_v = [&](int kt, short* dst) {
#pragma unroll
        for (int i = 0; i < 4; ++i) {
            const int L = i * 256 + tid;
            const int r = L >> 4, sc = ((L & 15) ^ (r & 7)) * 8;
            GLD16(Vt + (size_t)(bh * DKV + r) * SEQ + kt * 128 + sc,
                  dst + (size_t)(i * 256 + (w << 6)) * 8);
        }
    };
    auto qkt = [&](const short* Ks, f32x4 s[4][4]) {
#pragma unroll
        for (int m = 0; m < 4; ++m)
#pragma unroll
            for (int n = 0; n < 4; ++n) s[m][n] = {0.f, 0.f, 0.f, 0.f};
#pragma unroll
        for (int sk = 0; sk < 2; ++sk) {
            short8 qf[4], kf[4];
#pragma unroll
            for (int m = 0; m < 4; ++m) {
                const int r = wr + m * 16 + lrow;
                qf[m] = *(const short8*)((const char*)Qs + r * 128 + ((hi * 16 + sk * 64) ^ ((r & 7) << 4)));
            }
#pragma unroll
            for (int n = 0; n < 4; ++n) {
                const int r = wc2 * 64 + n * 16 + lrow;
                kf[n] = *(const short8*)((const char*)Ks + r * 128 + ((hi * 16 + sk * 64) ^ ((r & 7) << 4)));
            }
#pragma unroll
            for (int m = 0; m < 4; ++m)
#pragma unroll
                for (int n = 0; n < 4; ++n)
                    s[m][n] = __builtin_amdgcn_mfma_f32_16x16x32_bf16(kf[n], qf[m], s[m][n], 0, 0, 0);
        }
    };

    // ---- zero the strictly-upper tile region of our 128 rows (NT) ----
    {
        const int nz4 = (7 - it) * 32;               // f32x4s per row
        if (nz4 > 0) {
            const f32x4 z = {0.f, 0.f, 0.f, 0.f};
            for (int r = tid >> 5; r < 128; r += 8) {
                f32x4* rp = (f32x4*)(aprow + (size_t)(it * 128 + r) * SEQ + (it + 1) * 128);
                for (int c = tid & 31; c < nz4; c += 32)
                    __builtin_nontemporal_store(z, rp + c);
            }
        }
    }

    // ---- stage Q (once) + K[0] + V[0] ----
#pragma unroll
    for (int i = 0; i < 4; ++i) {
        const int L = i * 256 + tid;
        const int r = L >> 3, sc = ((L & 7) ^ (r & 7)) * 8;
        GLD16(Q + base + (size_t)(it * 128 + r) * QKLD + sc,
              Qs + (size_t)(i * 256 + (w << 6)) * 8);
    }
    stage_k(0, KVs[0]);
    stage_v(0, KVs[1]);
    __syncthreads();

    // ================= pass 1: rowsums + PV (unnormalized) =================
    float rs[4] = {0.f, 0.f, 0.f, 0.f};
    f32x4 o[4][2];
#pragma unroll
    for (int m = 0; m < 4; ++m)
#pragma unroll
        for (int n = 0; n < 2; ++n) o[m][n] = {0.f, 0.f, 0.f, 0.f};

    for (int kt = 0; kt <= it; ++kt) {
        f32x4 s[4][4];
        qkt(KVs[0], s);

        const bool diag = (kt == it);
#pragma unroll
        for (int m = 0; m < 4; ++m) {
            const int q = wr + m * 16 + lrow;
#pragma unroll
            for (int n = 0; n < 4; ++n) {
                const int k0 = wc2 * 64 + n * 16 + hi * 4;
                float p0 = exp2f(s[m][n][0]);
                float p1 = exp2f(s[m][n][1]);
                float p2 = exp2f(s[m][n][2]);
                float p3 = exp2f(s[m][n][3]);
                if (diag) {
                    if (k0 + 0 > q) p0 = 0.f;
                    if (k0 + 1 > q) p1 = 0.f;
                    if (k0 + 2 > q) p2 = 0.f;
                    if (k0 + 3 > q) p3 = 0.f;
                }
                rs[m] += (p0 + p1) + (p2 + p3);
                short4 ph = { f2bf(p0), f2bf(p1), f2bf(p2), f2bf(p3) };
                *(short4*)((char*)Ps + q * 256 + ((k0 * 2) ^ ((q & 7) << 4))) = ph;
            }
        }
        __syncthreads();                          // A: Ps visible, K buffer free
        if (kt < it) stage_k(kt + 1, KVs[0]);     // K[kt+1] flies under PV

        // PV: o += mfma(V, P) over full 128-k tile
#pragma unroll
        for (int sk = 0; sk < 4; ++sk) {
            short8 pf[4], vf[2];
#pragma unroll
            for (int m = 0; m < 4; ++m) {
                const int r = wr + m * 16 + lrow;
                pf[m] = *(const short8*)((const char*)Ps + r * 256 + ((hi * 16 + sk * 64) ^ ((r & 7) << 4)));
            }
#pragma unroll
            for (int n = 0; n < 2; ++n) {
                const int r = wc2 * 32 + n * 16 + lrow;
                vf[n] = *(const short8*)((const char*)KVs[1] + r * 256 + ((hi * 16 + sk * 64) ^ ((r & 7) << 4)));
            }
#pragma unroll
            for (int m = 0; m < 4; ++m)
#pragma unroll
                for (int n = 0; n < 2; ++n)
                    o[m][n] = __builtin_amdgcn_mfma_f32_16x16x32_bf16(vf[n], pf[m], o[m][n], 0, 0, 0);
        }
        __syncthreads();                          // B: drains K[kt+1]; V buffer free
        if (kt < it) stage_v(kt + 1, KVs[1]);     // V[kt+1] flies under next QK^T
    }

    // ---- rowsum reduce: lanes sharing lane&15 hold the same q-row ----
#pragma unroll
    for (int m = 0; m < 4; ++m) {
        rs[m] += __shfl_xor(rs[m], 16);
        rs[m] += __shfl_xor(rs[m], 32);
    }
    if (lane < 16) {
#pragma unroll
        for (int m = 0; m < 4; ++m)
            rsum[wc2 * 128 + wr + m * 16 + lane] = rs[m];
    }
    __syncthreads();
    if (tid < 128) rsum[tid] = 1.0f / (rsum[tid] + rsum[128 + tid]);
    __syncthreads();
    float inv[4];
#pragma unroll
    for (int m = 0; m < 4; ++m) inv[m] = rsum[wr + m * 16 + lrow];

    // ---- ctx = o * inv (bf16, short4) ----
#pragma unroll
    for (int m = 0; m < 4; ++m) {
        const int q = it * 128 + wr + m * 16 + lrow;
#pragma unroll
        for (int n = 0; n < 2; ++n) {
            const int d = h * DKV + wc2 * 32 + n * 16 + hi * 4;
            short4 st = { f2bf(o[m][n][0] * inv[m]), f2bf(o[m][n][1] * inv[m]),
                          f2bf(o[m][n][2] * inv[m]), f2bf(o[m][n][3] * inv[m]) };
            *(short4*)(ctx + (size_t)(b * SEQ + q) * DMODEL + d) = st;
        }
    }

    // ================= pass 2: write normalized P (K dbuf, 1 barrier/iter) ==
    stage_k(0, KVs[0]);
    __syncthreads();
    int cur = 0;
    for (int kt = 0; kt <= it; ++kt) {
        if (kt < it) stage_k(kt + 1, KVs[cur ^ 1]);

        f32x4 s[4][4];
        qkt(KVs[cur], s);

        const bool diag = (kt == it);
#pragma unroll
        for (int m = 0; m < 4; ++m) {
            const int q = wr + m * 16 + lrow;
#pragma unroll
            for (int n = 0; n < 4; ++n) {
                const int k0 = wc2 * 64 + n * 16 + hi * 4;
                float p0 = exp2f(s[m][n][0]);
                float p1 = exp2f(s[m][n][1]);
                float p2 = exp2f(s[m][n][2]);
                float p3 = exp2f(s[m][n][3]);
                if (diag) {
                    if (k0 + 0 > q) p0 = 0.f;
                    if (k0 + 1 > q) p1 = 0.f;
                    if (k0 + 2 > q) p2 = 0.f;
                    if (k0 + 3 > q) p3 = 0.f;
                }
                f32x4 pv4 = { p0 * inv[m], p1 * inv[m], p2 * inv[m], p3 * inv[m] };
                __builtin_nontemporal_store(pv4,
                    (f32x4*)(aprow + (size_t)(it * 128 + q) * SEQ + kt * 128 + k0));
            }
        }
        __syncthreads();            // drains next K tile; frees cur buffer
        cur ^= 1;
    }
}

// ---------------------------------------------------------------------------
// out = LayerNorm(xin + res)*g + b. xin f32 or bf16; res f32 or bf16;
// emits f32 and/or bf16.
// ---------------------------------------------------------------------------
template<int XIN_BF16, int RES_BF16, int OUT_F32, int OUT_BF16>
__global__ __launch_bounds__(128) void residual_ln(const void* __restrict__ xin,
                                                   const void* __restrict__ res,
                                                   const float* __restrict__ g,
                                                   const float* __restrict__ beta,
                                                   float* __restrict__ outf,
                                                   short* __restrict__ outh) {
    const int row = blockIdx.x;
    const int tid = threadIdx.x;

    float4 v;
    if (XIN_BF16) {
        const short4 xx = ((const short4*)((const short*)xin + (size_t)row * DMODEL))[tid];
        v.x = bf2f(xx.x); v.y = bf2f(xx.y); v.z = bf2f(xx.z); v.w = bf2f(xx.w);
    } else {
        v = ((const float4*)((const float*)xin + (size_t)row * DMODEL))[tid];
    }
    if (RES_BF16) {
        const short4 rr = ((const short4*)((const short*)res + (size_t)row * DMODEL))[tid];
        v.x += bf2f(rr.x); v.y += bf2f(rr.y); v.z += bf2f(rr.z); v.w += bf2f(rr.w);
    } else {
        const float4 rr = ((const float4*)((const float*)res + (size_t)row * DMODEL))[tid];
        v.x += rr.x; v.y += rr.y; v.z += rr.z; v.w += rr.w;
    }

    float sum = v.x + v.y + v.z + v.w;
    float sq  = v.x * v.x + v.y * v.y + v.z * v.z + v.w * v.w;
#pragma unroll
    for (int off = 32; off > 0; off >>= 1) {
        sum += __shfl_down(sum, off);
        sq  += __shfl_down(sq, off);
    }
    __shared__ float s_sum[2], s_sq[2];
    const int wid = tid >> 6, lane = tid & 63;
    if (lane == 0) { s_sum[wid] = sum; s_sq[wid] = sq; }
    __syncthreads();

    const float tsum = s_sum[0] + s_sum[1];
    const float tsq  = s_sq[0] + s_sq[1];
    const float mu   = tsum * (1.0f / DMODEL);
    const float var  = tsq * (1.0f / DMODEL) - mu * mu;
    const float rstd = rsqrtf(var + 1e-5f);

    const float4 gg = ((const float4*)g)[tid];
    const float4 bb = ((const float4*)beta)[tid];
    float4 o;
    o.x = (v.x - mu) * rstd * gg.x + bb.x;
    o.y = (v.y - mu) * rstd * gg.y + bb.y;
    o.z = (v.z - mu) * rstd * gg.z + bb.z;
    o.w = (v.w - mu) * rstd * gg.w + bb.w;
    if (OUT_F32) ((float4*)(outf + (size_t)row * DMODEL))[tid] = o;
    if (OUT_BF16) {
        short4 oh = { f2bf(o.x), f2bf(o.y), f2bf(o.z), f2bf(o.w) };
        ((short4*)(outh + (size_t)row * DMODEL))[tid] = oh;
    }
}

// ---------------------------------------------------------------------------
// Consolidated prep: all 6 weight transposes (32x32 tiles, f32 -> bf16
// transposed). X conversion not needed (QKV GEMM reads X directly).
// ---------------------------------------------------------------------------
__global__ __launch_bounds__(256) void prep_all(const float* __restrict__ w_q,
                                                const float* __restrict__ w_k,
                                                const float* __restrict__ w_v,
                                                const float* __restrict__ w_o,
                                                const float* __restrict__ w1,
                                                const float* __restrict__ w2,
                                                short* __restrict__ wqkvt,
                                                short* __restrict__ wot,
                                                short* __restrict__ w1t,
                                                short* __restrict__ w2t) {
    const int t = blockIdx.x;
    const int tid = threadIdx.x;
    const float* W; short* Wt; int K, N, tile;
    if (t < 1024) {                       // wq, wk, wv, wo (256 tiles each)
        const int wsel = t >> 8; tile = t & 255;
        K = 512; N = 512;
        W  = (wsel == 0) ? w_q : (wsel == 1) ? w_k : (wsel == 2) ? w_v : w_o;
        Wt = (wsel < 3) ? (wqkvt + (size_t)wsel * 512 * 512) : wot;
    } else if (t < 2048) { tile = t - 1024; K = 512;  N = 2048; W = w1; Wt = w1t; }
    else                 { tile = t - 2048; K = 2048; N = 512;  W = w2; Wt = w2t; }

    const int ntx = N >> 5;
    const int n0 = (tile % ntx) * 32, k0 = (tile / ntx) * 32;
    const int tx = tid & 31, ty = tid >> 5;

    __shared__ float tb[32][33];
#pragma unroll
    for (int i = 0; i < 4; ++i)
        tb[ty + i * 8][tx] = W[(size_t)(k0 + ty + i * 8) * N + n0 + tx];
    __syncthreads();
#pragma unroll
    for (int i = 0; i < 4; ++i)
        Wt[(size_t)(n0 + ty + i * 8) * K + k0 + tx] = f2bf(tb[tx][ty + i * 8]);
}

// ---------------------------------------------------------------------------
extern "C" void kernel_launch(void* const* d_in, const int* in_sizes, int n_in,
                              void* d_out, int out_size, void* d_ws, size_t ws_size,
                              hipStream_t stream) {
    const float* X    = (const float*)d_in[0];
    // d_in[1] = mask: causal triu -> handled analytically
    const float* w_q  = (const float*)d_in[2];
    const float* w_k  = (const float*)d_in[3];
    const float* w_v  = (const float*)d_in[4];
    const float* w_o  = (const float*)d_in[5];
    const float* ln1g = (const float*)d_in[6];
    const float* ln1b = (const float*)d_in[7];
    const float* w1   = (const float*)d_in[8];
    const float* w2   = (const float*)d_in[9];
    const float* ln2g = (const float*)d_in[10];
    const float* ln2b = (const float*)d_in[11];

    float* out   = (float*)d_out;                       // [8192, 512] f32
    float* attnP = out + (size_t)ROWS * DMODEL;         // [64, 1024, 1024] f32

    // workspace (shorts). M = 2^20 shorts = 2MB. Total 64MB.
    const size_t M = 1u << 20;
    short* ws    = (short*)d_ws;
    short* qkv   = ws;               // [ 0, 8M) Q|K [8192][1024]
    short* Vt    = ws + 8 * M;       // [ 8,12M) [64*64][1024] V^T
    short* ctxh  = ws + 12 * M;      // [12,16M)
    short* aoutH = ws + 16 * M;      // [16,20M)
    short* wqkvt = ws + 24 * M;      // [1536][512] = 0.75M shorts
    short* wot   = wqkvt + 786432;   // [512][512]  = 0.25M
    short* w1t   = ws + 25 * M;      // [2048][512] = 1M
    short* w2t   = ws + 26 * M;      // [512][2048] = 1M
    short* oph   = ws + 28 * M;      // [28,32M) out-proj bf16 (pre-LN1)
    short* ffnh  = ws + 28 * M;      // [28,32M) FFN2 bf16 (pre-LN2; oph dead)
    short* hbuf  = ws;               // [0,16M) FFN hidden [8192][2048]

    // prep: weight transposes (one dispatch)
    prep_all<<<dim3(3072), dim3(256), 0, stream>>>(w_q, w_k, w_v, w_o, w1, w2,
                                                   wqkvt, wot, w1t, w2t);

    // 1) fused QKV projection: A = X f32 (reg-staged + converted in-kernel);
    //    Q (scaled by log2e/8) | K -> qkv; V -> Vt transposed
    gemm_bt<1, 0, 1><<<dim3(12, 64), dim3(256), 0, stream>>>(X, wqkvt, qkv,
                                                             DMODEL, DMODEL, DMODEL, QKLD, 512, Vt);

    // 2) fused attention: ctx + attnP (probs incl. zeros, NT stores)
    fused_attn<<<dim3(8, 64), dim3(256), 0, stream>>>(qkv, qkv + 512, Vt, attnP, ctxh);

    // 3) out-proj (narrow-N: 512 blocks, bf16 -> oph) + LN1 (-> bf16 aoutH)
    gemm_n64<<<dim3(8, 64), dim3(256), 0, stream>>>(ctxh, wot, oph,
                                                    DMODEL, DMODEL, DMODEL, DMODEL);
    residual_ln<1, 0, 0, 1><<<dim3(ROWS), dim3(128), 0, stream>>>(oph, X, ln1g, ln1b, nullptr, aoutH);

    // 4) FFN: relu GEMM -> hbuf (bf16); FFN2 narrow-N -> ffnh (bf16); LN2 -> f32 out
    gemm_bt<1, 1, 0><<<dim3(16, 64), dim3(256), 0, stream>>>(aoutH, w1t, hbuf,
                                                             DMODEL, DMODEL, DMODEL, DFF, 0, nullptr);
    gemm_n64<<<dim3(8, 64), dim3(256), 0, stream>>>(hbuf, w2t, ffnh,
                                                    DFF, DFF, DFF, DMODEL);
    residual_ln<1, 1, 1, 0><<<dim3(ROWS), dim3(128), 0, stream>>>(ffnh, aoutH, ln2g, ln2b, out, nullptr);
}